// Round 4
// baseline (959.966 us; speedup 1.0000x reference)
//
#include <hip/hip_runtime.h>
#include <hip/hip_bf16.h>
#include <math.h>

#define EMB 64
#define SEQ 64
#define NH 8
#define DFF 256
#define VOC 32000
#define BATCH 64

using bf16_t = __hip_bfloat16;
typedef __bf16 bf16x8 __attribute__((ext_vector_type(8)));
typedef float f32x4 __attribute__((ext_vector_type(4)));

// ws layout (bytes)
#define WOUTT_OFF 0                     // bf16 [32000][64]  = 4,096,000 B
#define HBF_OFF   4194304               // bf16 [4096][64]   = 524,288 B
#define GSUM_OFF  (4194304 + 524288)    // f32  [4096]       = 16,384 B
#define GMAX_OFF  (4194304 + 524288 + 16384)  // u64 [4096]   = 32,768 B

// pack float (any sign) + index into an order-preserving u64 for atomicMax
__device__ inline unsigned long long packmax(float f, int i) {
  unsigned u = __float_as_uint(f);
  u = (u & 0x80000000u) ? ~u : (u | 0x80000000u);
  return ((unsigned long long)u << 32) | (unsigned)i;
}

// ---------- zero-fill out: plain (write-back) stores, harness-fill shape ----------
// NT stores measured ~1.4 TB/s on gfx950 (R2/R3 A/B); plain stores ~6.3 TB/s.
__global__ __launch_bounds__(256) void k_fill(float* __restrict__ outp) {
  const size_t nvec = (size_t)BATCH * SEQ * VOC / 4;  // 32,768,000 f32x4
  f32x4 z = {0.f, 0.f, 0.f, 0.f};
  f32x4* o4 = (f32x4*)outp;
  const size_t stride = (size_t)gridDim.x * 256;
  for (size_t i = (size_t)blockIdx.x * 256 + threadIdx.x; i < nvec; i += stride)
    o4[i] = z;
}

// ---------- small 64x64x64 GEMM helper: out = in(LDS,ld 65) @ W(global 64x64) ----------
template <int OP>  // 0: none, 1: rint
__device__ inline void gemm64t(const float* __restrict__ in, const float* __restrict__ W,
                               const float* __restrict__ bias, float* __restrict__ out,
                               int t) {
  int i = t >> 2, j0 = (t & 3) * 16;
  float acc[16];
#pragma unroll
  for (int j = 0; j < 16; ++j) acc[j] = 0.f;
  for (int k = 0; k < 64; ++k) {
    float a = in[i * 65 + k];
    const float4* wr = (const float4*)(W + k * 64 + j0);
    float4 w0 = wr[0], w1v = wr[1], w2v = wr[2], w3v = wr[3];
    acc[0] += a * w0.x;   acc[1] += a * w0.y;   acc[2] += a * w0.z;   acc[3] += a * w0.w;
    acc[4] += a * w1v.x;  acc[5] += a * w1v.y;  acc[6] += a * w1v.z;  acc[7] += a * w1v.w;
    acc[8] += a * w2v.x;  acc[9] += a * w2v.y;  acc[10] += a * w2v.z; acc[11] += a * w2v.w;
    acc[12] += a * w3v.x; acc[13] += a * w3v.y; acc[14] += a * w3v.z; acc[15] += a * w3v.w;
  }
#pragma unroll
  for (int j = 0; j < 16; ++j) {
    float v = acc[j] + (bias ? bias[j0 + j] : 0.f);
    if (OP == 1) v = rintf(v);
    out[i * 65 + j0 + j] = v;
  }
}

// ---------- fused kernel: blocks 0..63 run the transformer (b = blockIdx.x);
// blocks 64..563 transpose wout -> woutT bf16. ----------
__global__ __launch_bounds__(256) void k_prep(
    const int* __restrict__ x, const float* __restrict__ emb, const float* __restrict__ pe,
    const float* __restrict__ wq, const float* __restrict__ wk, const float* __restrict__ wv,
    const float* __restrict__ g_h, const float* __restrict__ b_h,
    const float* __restrict__ wo, const float* __restrict__ bo,
    const float* __restrict__ g1, const float* __restrict__ bt1,
    const float* __restrict__ w1, const float* __restrict__ b1f,
    const float* __restrict__ w2, const float* __restrict__ b2f,
    const float* __restrict__ g2, const float* __restrict__ bt2,
    const float* __restrict__ gf, const float* __restrict__ bf_,
    const float* __restrict__ wout, bf16_t* __restrict__ woutT,
    bf16_t* __restrict__ hbf, float* __restrict__ gsums,
    unsigned long long* __restrict__ gmax) {
  const int t = threadIdx.x;
  __shared__ float sm[6 * 64 * 65];   // 99.84 KB

  if (blockIdx.x >= 64) {
    // ---- transpose path: wout [64][32000] f32 -> woutT [32000][64] bf16 ----
    float* tile = sm;  // [64][65]
    int v0 = (blockIdx.x - 64) * 64;
    for (int idx = t; idx < 4096; idx += 256) {
      int e = idx >> 6, c = idx & 63;
      tile[e * 65 + c] = wout[(size_t)e * VOC + v0 + c];
    }
    __syncthreads();
    for (int idx = t; idx < 4096; idx += 256) {
      int c = idx >> 6, e = idx & 63;
      woutT[(size_t)(v0 + c) * 64 + e] = __float2bfloat16(tile[e * 65 + c]);
    }
    return;
  }

  // ---- transformer path ----
  const int b = blockIdx.x;
  if (t < 64) {
    gsums[b * 64 + t] = 0.f;     // zero row-sum accumulators
    gmax[b * 64 + t] = 0ULL;     // zero packed argmax accumulators
  }

  float* Hs = sm;                      // [64][65]
  float* Qs = sm + 4160;
  float* Ks = sm + 2 * 4160;
  float* Vs = sm + 3 * 4160;
  float* SC = sm + 4 * 4160;
  float* HO = sm + 5 * 4160;
  float* MID = sm + 4160;              // [64][260] overlays Qs..SC (16640 floats)

  // Stage 0: h = emb[x[b]] + pe
  for (int idx = t; idx < 4096; idx += 256) {
    int i = idx >> 6, e = idx & 63;
    int tok = x[b * 64 + i];
    Hs[i * 65 + e] = emb[(size_t)tok * 64 + e] + pe[i * 64 + e];
  }
  __syncthreads();

  // Stage 1: Q, K, V
  gemm64t<0>(Hs, wq, nullptr, Qs, t);
  gemm64t<0>(Hs, wk, nullptr, Ks, t);
  gemm64t<0>(Hs, wv, nullptr, Vs, t);
  __syncthreads();

  // Stage 2: attention per head (causal softmax, round4 on head outputs)
  const float scale = 0.35355339059327373f;  // 1/sqrt(8)
  for (int hh = 0; hh < NH; ++hh) {
    int qc = hh * 8;
    {
      int i = t >> 2, jb = t & 3;
      float qv[8];
#pragma unroll
      for (int d = 0; d < 8; ++d) qv[d] = Qs[i * 65 + qc + d];
      for (int jj = 0; jj < 16; ++jj) {
        int j = jb * 16 + jj;
        float s;
        if (j <= i) {
          s = 0.f;
#pragma unroll
          for (int d = 0; d < 8; ++d) s += qv[d] * Ks[j * 65 + qc + d];
          s *= scale;
        } else {
          s = -INFINITY;
        }
        SC[i * 65 + j] = s;
      }
    }
    __syncthreads();
    if (t < 64) {
      int i = t;
      float m = -INFINITY;
      for (int j = 0; j <= i; ++j) m = fmaxf(m, SC[i * 65 + j]);
      float sum = 0.f;
      for (int j = 0; j <= i; ++j) {
        float e2 = __expf(SC[i * 65 + j] - m);
        SC[i * 65 + j] = e2;
        sum += e2;
      }
      float inv = 1.f / sum;
      for (int j = 0; j <= i; ++j) SC[i * 65 + j] *= inv;
      for (int j = i + 1; j < 64; ++j) SC[i * 65 + j] = 0.f;
    }
    __syncthreads();
    for (int idx = t; idx < 512; idx += 256) {
      int i = idx >> 3, d = idx & 7;
      float o = 0.f;
      for (int j = 0; j < 64; ++j) o += SC[i * 65 + j] * Vs[j * 65 + qc + d];
      HO[i * 65 + qc + d] = rintf(o * 1e4f) / 1e4f;  // round4
    }
    __syncthreads();
  }

  // Stage 3: ln_h = layernorm(HO; g_h,b_h) -> SC ; attn_out = rint(SC@wo+bo) -> HO
  if (t < 64) {
    int i = t;
    float mu = 0.f;
    for (int e = 0; e < 64; ++e) mu += HO[i * 65 + e];
    mu *= (1.f / 64.f);
    float var = 0.f;
    for (int e = 0; e < 64; ++e) { float d = HO[i * 65 + e] - mu; var += d * d; }
    var *= (1.f / 64.f);
    float rs = rsqrtf(var + 1e-5f);
    for (int e = 0; e < 64; ++e) SC[i * 65 + e] = (HO[i * 65 + e] - mu) * rs * g_h[e] + b_h[e];
  }
  __syncthreads();
  gemm64t<1>(SC, wo, bo, HO, t);
  __syncthreads();

  // Stage 4: h1 = layernorm(Hs + HO; g1,bt1) -> Hs
  if (t < 64) {
    int i = t;
    for (int e = 0; e < 64; ++e) Hs[i * 65 + e] += HO[i * 65 + e];
    float mu = 0.f;
    for (int e = 0; e < 64; ++e) mu += Hs[i * 65 + e];
    mu *= (1.f / 64.f);
    float var = 0.f;
    for (int e = 0; e < 64; ++e) { float d = Hs[i * 65 + e] - mu; var += d * d; }
    var *= (1.f / 64.f);
    float rs = rsqrtf(var + 1e-5f);
    for (int e = 0; e < 64; ++e) Hs[i * 65 + e] = (Hs[i * 65 + e] - mu) * rs * g1[e] + bt1[e];
  }
  __syncthreads();

  // Stage 5: MID = relu(Hs @ w1 + b1f)  [64][260 pad]
  {
    int i = t >> 2, jq = t & 3;
    for (int c = 0; c < 4; ++c) {
      int j0 = jq * 64 + c * 16;
      float acc[16];
#pragma unroll
      for (int j = 0; j < 16; ++j) acc[j] = 0.f;
      for (int k = 0; k < 64; ++k) {
        float a = Hs[i * 65 + k];
        const float4* wr = (const float4*)(w1 + (size_t)k * 256 + j0);
        float4 w0 = wr[0], w1v = wr[1], w2v = wr[2], w3v = wr[3];
        acc[0] += a * w0.x;   acc[1] += a * w0.y;   acc[2] += a * w0.z;   acc[3] += a * w0.w;
        acc[4] += a * w1v.x;  acc[5] += a * w1v.y;  acc[6] += a * w1v.z;  acc[7] += a * w1v.w;
        acc[8] += a * w2v.x;  acc[9] += a * w2v.y;  acc[10] += a * w2v.z; acc[11] += a * w2v.w;
        acc[12] += a * w3v.x; acc[13] += a * w3v.y; acc[14] += a * w3v.z; acc[15] += a * w3v.w;
      }
#pragma unroll
      for (int j = 0; j < 16; ++j)
        MID[i * 260 + j0 + j] = fmaxf(acc[j] + b1f[j0 + j], 0.f);
    }
  }
  __syncthreads();

  // Stage 6: ffn_out = MID @ w2 + b2f -> HO
  {
    int i = t >> 2, j0 = (t & 3) * 16;
    float acc[16];
#pragma unroll
    for (int j = 0; j < 16; ++j) acc[j] = 0.f;
    for (int k = 0; k < 256; ++k) {
      float a = MID[i * 260 + k];
      const float4* wr = (const float4*)(w2 + (size_t)k * 64 + j0);
      float4 w0 = wr[0], w1v = wr[1], w2v = wr[2], w3v = wr[3];
      acc[0] += a * w0.x;   acc[1] += a * w0.y;   acc[2] += a * w0.z;   acc[3] += a * w0.w;
      acc[4] += a * w1v.x;  acc[5] += a * w1v.y;  acc[6] += a * w1v.z;  acc[7] += a * w1v.w;
      acc[8] += a * w2v.x;  acc[9] += a * w2v.y;  acc[10] += a * w2v.z; acc[11] += a * w2v.w;
      acc[12] += a * w3v.x; acc[13] += a * w3v.y; acc[14] += a * w3v.z; acc[15] += a * w3v.w;
    }
#pragma unroll
    for (int j = 0; j < 16; ++j) HO[i * 65 + j0 + j] = acc[j] + b2f[j0 + j];
  }
  __syncthreads();

  // Stage 7: h2 = round4(layernorm(Hs + HO; g2,bt2)) -> Hs ; hf = layernorm(Hs; gf,bf) -> SC
  if (t < 64) {
    int i = t;
    for (int e = 0; e < 64; ++e) Hs[i * 65 + e] += HO[i * 65 + e];
    float mu = 0.f;
    for (int e = 0; e < 64; ++e) mu += Hs[i * 65 + e];
    mu *= (1.f / 64.f);
    float var = 0.f;
    for (int e = 0; e < 64; ++e) { float d = Hs[i * 65 + e] - mu; var += d * d; }
    var *= (1.f / 64.f);
    float rs = rsqrtf(var + 1e-5f);
    for (int e = 0; e < 64; ++e)
      Hs[i * 65 + e] = rintf(((Hs[i * 65 + e] - mu) * rs * g2[e] + bt2[e]) * 1e4f) / 1e4f;
    float mu2 = 0.f;
    for (int e = 0; e < 64; ++e) mu2 += Hs[i * 65 + e];
    mu2 *= (1.f / 64.f);
    float var2 = 0.f;
    for (int e = 0; e < 64; ++e) { float d = Hs[i * 65 + e] - mu2; var2 += d * d; }
    var2 *= (1.f / 64.f);
    float rs2 = rsqrtf(var2 + 1e-5f);
    for (int e = 0; e < 64; ++e) SC[i * 65 + e] = (Hs[i * 65 + e] - mu2) * rs2 * gf[e] + bf_[e];
  }
  __syncthreads();

  // Stage 8: hf -> bf16 global
  for (int idx = t; idx < 4096; idx += 256) {
    int i = idx >> 6, e = idx & 63;
    hbf[((size_t)b * 64 + i) * 64 + e] = __float2bfloat16(SC[i * 65 + e]);
  }
}

// ---------- kernel A: per-row sum of exp(logit) over V + running argmax, MFMA ----------
// 64 rows per block (4 A-row-tiles share each B-tile load): grid (64, 8)
__global__ __launch_bounds__(256) void k_sumexp(const bf16_t* __restrict__ hbf,
                                                const bf16_t* __restrict__ woutT,
                                                const float* __restrict__ bout,
                                                float* __restrict__ gsums,
                                                unsigned long long* __restrict__ gmax) {
  const int t = threadIdx.x;
  const int lane = t & 63, wave = t >> 6;
  const int row0 = blockIdx.x * 64;
  const int nbase = blockIdx.y * 4000;
  const int mrow = lane & 15, quad = lane >> 4;
  __shared__ float lsum[64];
  if (t < 64) lsum[t] = 0.f;
  __syncthreads();

  bf16x8 a0[4], a1[4];
#pragma unroll
  for (int at = 0; at < 4; ++at) {
    const bf16_t* arow = hbf + (size_t)(row0 + at * 16 + mrow) * 64 + quad * 8;
    a0[at] = *(const bf16x8*)(arow);
    a1[at] = *(const bf16x8*)(arow + 32);
  }

  float s[4][4];
  float mxv[4][4];
  int mxi[4][4];
#pragma unroll
  for (int at = 0; at < 4; ++at)
#pragma unroll
    for (int r = 0; r < 4; ++r) { s[at][r] = 0.f; mxv[at][r] = -INFINITY; mxi[at][r] = 0; }

  for (int tt = wave; tt < 250; tt += 4) {
    int col = nbase + tt * 16 + mrow;
    const bf16_t* brow = woutT + (size_t)col * 64 + quad * 8;
    bf16x8 b0 = *(const bf16x8*)(brow);
    bf16x8 b1 = *(const bf16x8*)(brow + 32);
    float bv = bout[col];
#pragma unroll
    for (int at = 0; at < 4; ++at) {
      f32x4 c = {0.f, 0.f, 0.f, 0.f};
      c = __builtin_amdgcn_mfma_f32_16x16x32_bf16(a0[at], b0, c, 0, 0, 0);
      c = __builtin_amdgcn_mfma_f32_16x16x32_bf16(a1[at], b1, c, 0, 0, 0);
#pragma unroll
      for (int r = 0; r < 4; ++r) {
        float v = c[r] + bv;
        s[at][r] += __expf(v);
        mxi[at][r] = (v > mxv[at][r]) ? col : mxi[at][r];
        mxv[at][r] = fmaxf(mxv[at][r], v);
      }
    }
  }
  // reduce over the 16 lanes of each quad (C cols); rows = at*16 + quad*4 + reg
#pragma unroll
  for (int off = 1; off < 16; off <<= 1) {
#pragma unroll
    for (int at = 0; at < 4; ++at)
#pragma unroll
      for (int r = 0; r < 4; ++r) {
        s[at][r] += __shfl_xor(s[at][r], off, 64);
        float ov = __shfl_xor(mxv[at][r], off, 64);
        int oi = __shfl_xor(mxi[at][r], off, 64);
        if (ov > mxv[at][r] || (ov == mxv[at][r] && oi > mxi[at][r])) {
          mxv[at][r] = ov; mxi[at][r] = oi;
        }
      }
  }
  if (mrow == 0) {
#pragma unroll
    for (int at = 0; at < 4; ++at)
#pragma unroll
      for (int r = 0; r < 4; ++r) {
        atomicAdd(&lsum[at * 16 + quad * 4 + r], s[at][r]);
        atomicMax(&gmax[row0 + at * 16 + quad * 4 + r], packmax(mxv[at][r], mxi[at][r]));
      }
  }
  __syncthreads();
  if (t < 64) atomicAdd(&gsums[row0 + t], lsum[t]);
}

// ---------- kernel B: scatter the (at most one) nonzero per row ----------
// rint(p) with p in [0,1] is 1 iff p > 0.5; only the row-argmax can satisfy it.
__global__ __launch_bounds__(256) void k_scatter(const float* __restrict__ gsums,
                                                 const unsigned long long* __restrict__ gmax,
                                                 float* __restrict__ out) {
  int row = blockIdx.x * 256 + threadIdx.x;
  if (row >= BATCH * SEQ) return;
  unsigned long long p = gmax[row];
  unsigned key = (unsigned)(p >> 32);
  int idx = (int)(p & 0xffffffffu);
  unsigned ub = (key & 0x80000000u) ? (key & 0x7fffffffu) : ~key;
  float lmax = __uint_as_float(ub);
  float iv = 1.0f / gsums[row];
  float v = rintf(__expf(lmax) * iv);   // identical float path to old k_probs
  if (v != 0.0f) out[(size_t)row * VOC + idx] = v;
}

extern "C" void kernel_launch(void* const* d_in, const int* in_sizes, int n_in,
                              void* d_out, int out_size, void* d_ws, size_t ws_size,
                              hipStream_t stream) {
  const int* x = (const int*)d_in[0];
  const float* emb = (const float*)d_in[1];
  const float* pe = (const float*)d_in[2];
  const float* wq = (const float*)d_in[3];
  const float* wk = (const float*)d_in[4];
  const float* wv = (const float*)d_in[5];
  const float* g_h = (const float*)d_in[6];
  const float* b_h = (const float*)d_in[7];
  const float* wo = (const float*)d_in[8];
  const float* bo = (const float*)d_in[9];
  const float* g1 = (const float*)d_in[10];
  const float* bt1 = (const float*)d_in[11];
  const float* w1 = (const float*)d_in[12];
  const float* b1f = (const float*)d_in[13];
  const float* w2 = (const float*)d_in[14];
  const float* b2f = (const float*)d_in[15];
  const float* g2 = (const float*)d_in[16];
  const float* bt2 = (const float*)d_in[17];
  const float* gf = (const float*)d_in[18];
  const float* bff = (const float*)d_in[19];
  const float* wout = (const float*)d_in[20];
  const float* bout = (const float*)d_in[21];

  char* ws = (char*)d_ws;
  bf16_t* woutT = (bf16_t*)(ws + WOUTT_OFF);
  bf16_t* hbf = (bf16_t*)(ws + HBF_OFF);
  float* gsums = (float*)(ws + GSUM_OFF);
  unsigned long long* gmax = (unsigned long long*)(ws + GMAX_OFF);
  float* out = (float*)d_out;

  k_fill<<<2048, 256, 0, stream>>>(out);
  k_prep<<<564, 256, 0, stream>>>(x, emb, pe, wq, wk, wv, g_h, b_h, wo, bo,
                                  g1, bt1, w1, b1f, w2, b2f, g2, bt2, gf, bff,
                                  wout, woutT, hbf, gsums, gmax);
  dim3 grid(64, 8);
  k_sumexp<<<grid, 256, 0, stream>>>(hbf, woutT, bout, gsums, gmax);
  k_scatter<<<16, 256, 0, stream>>>(gsums, gmax, out);
}

// Round 6
// 757.320 us; speedup vs baseline: 1.2676x; 1.2676x over previous
//
#include <hip/hip_runtime.h>
#include <hip/hip_bf16.h>
#include <math.h>

#define EMB 64
#define SEQ 64
#define NH 8
#define DFF 256
#define VOC 32000
#define BATCH 64

using bf16_t = __hip_bfloat16;
typedef __bf16 bf16x8 __attribute__((ext_vector_type(8)));
typedef float f32x4 __attribute__((ext_vector_type(4)));

// ws layout (bytes)
#define WOUTT_OFF 0                     // bf16 [32000][64]  = 4,096,000 B
#define HBF_OFF   4194304               // bf16 [4096][64]   = 524,288 B
#define GSUM_OFF  (4194304 + 524288)    // f32  [4096]       = 16,384 B
#define GMAX_OFF  (GSUM_OFF + 16384)    // u64  [4096]       = 32,768 B
#define H_OFF     (GMAX_OFF + 32768)    // f32  [4096][64]   = 1 MB
#define Q_OFF     (H_OFF + 1048576)
#define K_OFF     (Q_OFF + 1048576)
#define V_OFF     (K_OFF + 1048576)
#define HO_OFF    (V_OFF + 1048576)     // ends at ~9.99 MB

// pack float (any sign) + index into an order-preserving u64 for atomicMax
__device__ inline unsigned long long packmax(float f, int i) {
  unsigned u = __float_as_uint(f);
  u = (u & 0x80000000u) ? ~u : (u | 0x80000000u);
  return ((unsigned long long)u << 32) | (unsigned)i;
}

__device__ inline float rsum16(float s) {
  s += __shfl_xor(s, 1, 16);
  s += __shfl_xor(s, 2, 16);
  s += __shfl_xor(s, 4, 16);
  s += __shfl_xor(s, 8, 16);
  return s;
}

// 64x64x64 GEMM from LDS (ld 65) to GLOBAL out (row stride 64), no bias
__device__ inline void gemm64g(const float* __restrict__ in, const float* __restrict__ W,
                               float* __restrict__ out, int t) {
  int i = t >> 2, j0 = (t & 3) * 16;
  float acc[16];
#pragma unroll
  for (int j = 0; j < 16; ++j) acc[j] = 0.f;
#pragma unroll 2
  for (int k = 0; k < 64; ++k) {
    float a = in[i * 65 + k];
    const float4* wr = (const float4*)(W + k * 64 + j0);
    float4 w0 = wr[0], w1v = wr[1], w2v = wr[2], w3v = wr[3];
    acc[0] += a * w0.x;   acc[1] += a * w0.y;   acc[2] += a * w0.z;   acc[3] += a * w0.w;
    acc[4] += a * w1v.x;  acc[5] += a * w1v.y;  acc[6] += a * w1v.z;  acc[7] += a * w1v.w;
    acc[8] += a * w2v.x;  acc[9] += a * w2v.y;  acc[10] += a * w2v.z; acc[11] += a * w2v.w;
    acc[12] += a * w3v.x; acc[13] += a * w3v.y; acc[14] += a * w3v.z; acc[15] += a * w3v.w;
  }
#pragma unroll
  for (int j = 0; j < 16; ++j) out[(size_t)i * 64 + j0 + j] = acc[j];
}

// ---------- K1: blocks 0..63 emb+pe -> H + QKV GEMMs; 64..563 wout transpose;
// 564..1587 zero-fill out. Small LDS (16.6 KB) -> fill runs at high occupancy
// and overlaps the compute blocks. ----------
__global__ __launch_bounds__(256) void k_qkv(
    const int* __restrict__ x, const float* __restrict__ emb, const float* __restrict__ pe,
    const float* __restrict__ wq, const float* __restrict__ wk, const float* __restrict__ wv,
    const float* __restrict__ wout, bf16_t* __restrict__ woutT,
    float* __restrict__ H, float* __restrict__ Q, float* __restrict__ K,
    float* __restrict__ V, float* __restrict__ gsums,
    unsigned long long* __restrict__ gmax, float* __restrict__ outp) {
  const int t = threadIdx.x;
  __shared__ float sm[64 * 65];

  if (blockIdx.x >= 564) {
    // ---- zero-fill path: 1024 blocks x 32000 f32x4 contiguous slices ----
    const int bid = blockIdx.x - 564;
    f32x4 z = {0.f, 0.f, 0.f, 0.f};
    f32x4* o4 = (f32x4*)outp + (size_t)bid * 32000;
    for (int i = t; i < 32000; i += 256) o4[i] = z;
    return;
  }

  if (blockIdx.x >= 64) {
    // ---- transpose path: wout [64][32000] f32 -> woutT [32000][64] bf16 ----
    int v0 = (blockIdx.x - 64) * 64;
    for (int idx = t; idx < 4096; idx += 256) {
      int e = idx >> 6, c = idx & 63;
      sm[e * 65 + c] = wout[(size_t)e * VOC + v0 + c];
    }
    __syncthreads();
    for (int idx = t; idx < 4096; idx += 256) {
      int c = idx >> 6, e = idx & 63;
      woutT[(size_t)(v0 + c) * 64 + e] = __float2bfloat16(sm[e * 65 + c]);
    }
    return;
  }

  // ---- QKV path ----
  const int b = blockIdx.x;
  if (t < 64) {
    gsums[b * 64 + t] = 0.f;
    gmax[b * 64 + t] = 0ULL;
  }
  for (int idx = t; idx < 4096; idx += 256) {
    int i = idx >> 6, e = idx & 63;
    int tok = x[b * 64 + i];
    float v = emb[(size_t)tok * 64 + e] + pe[i * 64 + e];
    sm[i * 65 + e] = v;
    H[((size_t)b * 64 + i) * 64 + e] = v;
  }
  __syncthreads();
  gemm64g(sm, wq, Q + (size_t)b * 4096, t);
  gemm64g(sm, wk, K + (size_t)b * 4096, t);
  gemm64g(sm, wv, V + (size_t)b * 4096, t);
}

// ---------- K2: attention, one block per (b, head). Wave-parallel softmax. ----------
__global__ __launch_bounds__(256) void k_attn(const float* __restrict__ Q,
                                              const float* __restrict__ K,
                                              const float* __restrict__ V,
                                              float* __restrict__ HO) {
  const int b = blockIdx.x, h = blockIdx.y;
  const int t = threadIdx.x;
  __shared__ float Qh[64 * 8], Kh[64 * 8], Vh[64 * 8];
  __shared__ float SC[64 * 65];
  const size_t base = (size_t)b * 4096 + h * 8;

  for (int idx = t; idx < 512; idx += 256) {
    int i = idx >> 3, d = idx & 7;
    Qh[i * 8 + d] = Q[base + (size_t)i * 64 + d];
    Kh[i * 8 + d] = K[base + (size_t)i * 64 + d];
    Vh[i * 8 + d] = V[base + (size_t)i * 64 + d];
  }
  __syncthreads();

  const float scale = 0.35355339059327373f;  // 1/sqrt(8)
  const int i = t >> 2, jb = t & 3;
  float qv[8];
#pragma unroll
  for (int d = 0; d < 8; ++d) qv[d] = Qh[i * 8 + d];

  float sv[16];
  float m = -INFINITY;
#pragma unroll
  for (int jj = 0; jj < 16; ++jj) {
    int j = jb * 16 + jj;
    float s;
    if (j <= i) {
      s = 0.f;
#pragma unroll
      for (int d = 0; d < 8; ++d) s += qv[d] * Kh[j * 8 + d];
      s *= scale;
    } else {
      s = -INFINITY;
    }
    sv[jj] = s;
    m = fmaxf(m, s);
  }
  // row reduce over the 4 lanes holding row i
  m = fmaxf(m, __shfl_xor(m, 1, 4));
  m = fmaxf(m, __shfl_xor(m, 2, 4));
  float sum = 0.f;
#pragma unroll
  for (int jj = 0; jj < 16; ++jj) {
    float e2 = __expf(sv[jj] - m);   // exp(-inf - m) = 0 for masked j
    sv[jj] = e2;
    sum += e2;
  }
  sum += __shfl_xor(sum, 1, 4);
  sum += __shfl_xor(sum, 2, 4);
  float inv = 1.f / sum;
#pragma unroll
  for (int jj = 0; jj < 16; ++jj) SC[i * 65 + jb * 16 + jj] = sv[jj] * inv;
  __syncthreads();

  for (int idx = t; idx < 512; idx += 256) {
    int ii = idx >> 3, d = idx & 7;
    float o = 0.f;
    for (int j = 0; j < 64; ++j) o += SC[ii * 65 + j] * Vh[j * 8 + d];
    HO[base + (size_t)ii * 64 + d] = rintf(o * 1e4f) / 1e4f;  // round4
  }
}

// ---------- K3: per-row LN/wo/residual/FFN/LN chain, 16 rows per block. ----------
__global__ __launch_bounds__(256) void k_ffn(
    const float* __restrict__ H, const float* __restrict__ HO,
    const float* __restrict__ g_h, const float* __restrict__ b_h,
    const float* __restrict__ wo, const float* __restrict__ bo,
    const float* __restrict__ g1, const float* __restrict__ bt1,
    const float* __restrict__ w1, const float* __restrict__ b1f,
    const float* __restrict__ w2, const float* __restrict__ b2f,
    const float* __restrict__ g2, const float* __restrict__ bt2,
    const float* __restrict__ gf, const float* __restrict__ bf_,
    bf16_t* __restrict__ hbf) {
  const int t = threadIdx.x;
  const int r0 = blockIdx.x * 16;
  const int i = t >> 4, l = t & 15;    // row-in-block, lane-in-row
  const int e0 = l * 4;
  const size_t row = (size_t)(r0 + i) * 64;
  __shared__ float T1[16 * 65];
  __shared__ float T2[16 * 65];
  __shared__ float H1[16 * 65];
  __shared__ float M[16 * 260];

  // A: ln_h = layernorm(HO; g_h, b_h) -> T1
  {
    float4 hv = *(const float4*)(HO + row + e0);
    float mu = rsum16(hv.x + hv.y + hv.z + hv.w) * (1.f / 64.f);
    float d0 = hv.x - mu, d1 = hv.y - mu, d2 = hv.z - mu, d3 = hv.w - mu;
    float var = rsum16(d0 * d0 + d1 * d1 + d2 * d2 + d3 * d3) * (1.f / 64.f);
    float rs = rsqrtf(var + 1e-5f);
    T1[i * 65 + e0 + 0] = d0 * rs * g_h[e0 + 0] + b_h[e0 + 0];
    T1[i * 65 + e0 + 1] = d1 * rs * g_h[e0 + 1] + b_h[e0 + 1];
    T1[i * 65 + e0 + 2] = d2 * rs * g_h[e0 + 2] + b_h[e0 + 2];
    T1[i * 65 + e0 + 3] = d3 * rs * g_h[e0 + 3] + b_h[e0 + 3];
  }
  __syncthreads();

  // B: attn_out = rint(T1 @ wo + bo) -> T2
  {
    float a0 = 0.f, a1 = 0.f, a2 = 0.f, a3 = 0.f;
#pragma unroll 4
    for (int k = 0; k < 64; ++k) {
      float a = T1[i * 65 + k];
      float4 w = *(const float4*)(wo + (size_t)k * 64 + e0);
      a0 += a * w.x; a1 += a * w.y; a2 += a * w.z; a3 += a * w.w;
    }
    T2[i * 65 + e0 + 0] = rintf(a0 + bo[e0 + 0]);
    T2[i * 65 + e0 + 1] = rintf(a1 + bo[e0 + 1]);
    T2[i * 65 + e0 + 2] = rintf(a2 + bo[e0 + 2]);
    T2[i * 65 + e0 + 3] = rintf(a3 + bo[e0 + 3]);
  }
  __syncthreads();

  // C: h1 = layernorm(H + attn_out; g1, bt1) -> H1
  {
    float4 hh = *(const float4*)(H + row + e0);
    float x0 = hh.x + T2[i * 65 + e0 + 0];
    float x1 = hh.y + T2[i * 65 + e0 + 1];
    float x2 = hh.z + T2[i * 65 + e0 + 2];
    float x3 = hh.w + T2[i * 65 + e0 + 3];
    float mu = rsum16(x0 + x1 + x2 + x3) * (1.f / 64.f);
    float d0 = x0 - mu, d1 = x1 - mu, d2 = x2 - mu, d3 = x3 - mu;
    float var = rsum16(d0 * d0 + d1 * d1 + d2 * d2 + d3 * d3) * (1.f / 64.f);
    float rs = rsqrtf(var + 1e-5f);
    H1[i * 65 + e0 + 0] = d0 * rs * g1[e0 + 0] + bt1[e0 + 0];
    H1[i * 65 + e0 + 1] = d1 * rs * g1[e0 + 1] + bt1[e0 + 1];
    H1[i * 65 + e0 + 2] = d2 * rs * g1[e0 + 2] + bt1[e0 + 2];
    H1[i * 65 + e0 + 3] = d3 * rs * g1[e0 + 3] + bt1[e0 + 3];
  }
  __syncthreads();

  // D: M = relu(H1 @ w1 + b1f), 16 outputs per thread (j0 = l*16)
  {
    const int j0 = l * 16;
    float acc[16];
#pragma unroll
    for (int j = 0; j < 16; ++j) acc[j] = 0.f;
#pragma unroll 2
    for (int k = 0; k < 64; ++k) {
      float a = H1[i * 65 + k];
      const float4* wr = (const float4*)(w1 + (size_t)k * 256 + j0);
      float4 w0 = wr[0], w1v = wr[1], w2v = wr[2], w3v = wr[3];
      acc[0] += a * w0.x;   acc[1] += a * w0.y;   acc[2] += a * w0.z;   acc[3] += a * w0.w;
      acc[4] += a * w1v.x;  acc[5] += a * w1v.y;  acc[6] += a * w1v.z;  acc[7] += a * w1v.w;
      acc[8] += a * w2v.x;  acc[9] += a * w2v.y;  acc[10] += a * w2v.z; acc[11] += a * w2v.w;
      acc[12] += a * w3v.x; acc[13] += a * w3v.y; acc[14] += a * w3v.z; acc[15] += a * w3v.w;
    }
#pragma unroll
    for (int j = 0; j < 16; ++j)
      M[i * 260 + j0 + j] = fmaxf(acc[j] + b1f[j0 + j], 0.f);
  }
  __syncthreads();

  // E: ffn = M @ w2 + b2f (kept in regs)
  float f0 = 0.f, f1 = 0.f, f2 = 0.f, f3 = 0.f;
  {
#pragma unroll 4
    for (int k = 0; k < 256; ++k) {
      float a = M[i * 260 + k];
      float4 w = *(const float4*)(w2 + (size_t)k * 64 + e0);
      f0 += a * w.x; f1 += a * w.y; f2 += a * w.z; f3 += a * w.w;
    }
    f0 += b2f[e0 + 0]; f1 += b2f[e0 + 1]; f2 += b2f[e0 + 2]; f3 += b2f[e0 + 3];
  }

  // F: h2 = round4(layernorm(H1 + ffn; g2, bt2)); hf = layernorm(h2; gf, bf) -> hbf
  {
    float y0 = H1[i * 65 + e0 + 0] + f0;
    float y1 = H1[i * 65 + e0 + 1] + f1;
    float y2 = H1[i * 65 + e0 + 2] + f2;
    float y3 = H1[i * 65 + e0 + 3] + f3;
    float mu = rsum16(y0 + y1 + y2 + y3) * (1.f / 64.f);
    float d0 = y0 - mu, d1 = y1 - mu, d2 = y2 - mu, d3 = y3 - mu;
    float var = rsum16(d0 * d0 + d1 * d1 + d2 * d2 + d3 * d3) * (1.f / 64.f);
    float rs = rsqrtf(var + 1e-5f);
    float h20 = rintf((d0 * rs * g2[e0 + 0] + bt2[e0 + 0]) * 1e4f) / 1e4f;
    float h21 = rintf((d1 * rs * g2[e0 + 1] + bt2[e0 + 1]) * 1e4f) / 1e4f;
    float h22 = rintf((d2 * rs * g2[e0 + 2] + bt2[e0 + 2]) * 1e4f) / 1e4f;
    float h23 = rintf((d3 * rs * g2[e0 + 3] + bt2[e0 + 3]) * 1e4f) / 1e4f;
    float mu2 = rsum16(h20 + h21 + h22 + h23) * (1.f / 64.f);
    float e0d = h20 - mu2, e1d = h21 - mu2, e2d = h22 - mu2, e3d = h23 - mu2;
    float var2 = rsum16(e0d * e0d + e1d * e1d + e2d * e2d + e3d * e3d) * (1.f / 64.f);
    float rs2 = rsqrtf(var2 + 1e-5f);
    hbf[row + e0 + 0] = __float2bfloat16(e0d * rs2 * gf[e0 + 0] + bf_[e0 + 0]);
    hbf[row + e0 + 1] = __float2bfloat16(e1d * rs2 * gf[e0 + 1] + bf_[e0 + 1]);
    hbf[row + e0 + 2] = __float2bfloat16(e2d * rs2 * gf[e0 + 2] + bf_[e0 + 2]);
    hbf[row + e0 + 3] = __float2bfloat16(e3d * rs2 * gf[e0 + 3] + bf_[e0 + 3]);
  }
}

// ---------- kernel A: per-row sum of exp(logit) over V + running argmax, MFMA ----------
// 64 rows per block (4 A-row-tiles share each B-tile load): grid (64, 8)
__global__ __launch_bounds__(256) void k_sumexp(const bf16_t* __restrict__ hbf,
                                                const bf16_t* __restrict__ woutT,
                                                const float* __restrict__ bout,
                                                float* __restrict__ gsums,
                                                unsigned long long* __restrict__ gmax) {
  const int t = threadIdx.x;
  const int lane = t & 63, wave = t >> 6;
  const int row0 = blockIdx.x * 64;
  const int nbase = blockIdx.y * 4000;
  const int mrow = lane & 15, quad = lane >> 4;
  __shared__ float lsum[64];
  if (t < 64) lsum[t] = 0.f;
  __syncthreads();

  bf16x8 a0[4], a1[4];
#pragma unroll
  for (int at = 0; at < 4; ++at) {
    const bf16_t* arow = hbf + (size_t)(row0 + at * 16 + mrow) * 64 + quad * 8;
    a0[at] = *(const bf16x8*)(arow);
    a1[at] = *(const bf16x8*)(arow + 32);
  }

  float s[4][4];
  float mxv[4][4];
  int mxi[4][4];
#pragma unroll
  for (int at = 0; at < 4; ++at)
#pragma unroll
    for (int r = 0; r < 4; ++r) { s[at][r] = 0.f; mxv[at][r] = -INFINITY; mxi[at][r] = 0; }

  for (int tt = wave; tt < 250; tt += 4) {
    int col = nbase + tt * 16 + mrow;
    const bf16_t* brow = woutT + (size_t)col * 64 + quad * 8;
    bf16x8 b0 = *(const bf16x8*)(brow);
    bf16x8 b1 = *(const bf16x8*)(brow + 32);
    float bv = bout[col];
#pragma unroll
    for (int at = 0; at < 4; ++at) {
      f32x4 c = {0.f, 0.f, 0.f, 0.f};
      c = __builtin_amdgcn_mfma_f32_16x16x32_bf16(a0[at], b0, c, 0, 0, 0);
      c = __builtin_amdgcn_mfma_f32_16x16x32_bf16(a1[at], b1, c, 0, 0, 0);
#pragma unroll
      for (int r = 0; r < 4; ++r) {
        float v = c[r] + bv;
        s[at][r] += __expf(v);
        mxi[at][r] = (v > mxv[at][r]) ? col : mxi[at][r];
        mxv[at][r] = fmaxf(mxv[at][r], v);
      }
    }
  }
#pragma unroll
  for (int off = 1; off < 16; off <<= 1) {
#pragma unroll
    for (int at = 0; at < 4; ++at)
#pragma unroll
      for (int r = 0; r < 4; ++r) {
        s[at][r] += __shfl_xor(s[at][r], off, 64);
        float ov = __shfl_xor(mxv[at][r], off, 64);
        int oi = __shfl_xor(mxi[at][r], off, 64);
        if (ov > mxv[at][r] || (ov == mxv[at][r] && oi > mxi[at][r])) {
          mxv[at][r] = ov; mxi[at][r] = oi;
        }
      }
  }
  if (mrow == 0) {
#pragma unroll
    for (int at = 0; at < 4; ++at)
#pragma unroll
      for (int r = 0; r < 4; ++r) {
        atomicAdd(&lsum[at * 16 + quad * 4 + r], s[at][r]);
        atomicMax(&gmax[row0 + at * 16 + quad * 4 + r], packmax(mxv[at][r], mxi[at][r]));
      }
  }
  __syncthreads();
  if (t < 64) atomicAdd(&gsums[row0 + t], lsum[t]);
}

// ---------- kernel B: scatter the (at most one) nonzero per row ----------
__global__ __launch_bounds__(256) void k_scatter(const float* __restrict__ gsums,
                                                 const unsigned long long* __restrict__ gmax,
                                                 float* __restrict__ out) {
  int row = blockIdx.x * 256 + threadIdx.x;
  if (row >= BATCH * SEQ) return;
  unsigned long long p = gmax[row];
  unsigned key = (unsigned)(p >> 32);
  int idx = (int)(p & 0xffffffffu);
  unsigned ub = (key & 0x80000000u) ? (key & 0x7fffffffu) : ~key;
  float lmax = __uint_as_float(ub);
  float iv = 1.0f / gsums[row];
  float v = rintf(__expf(lmax) * iv);
  if (v != 0.0f) out[(size_t)row * VOC + idx] = v;
}

extern "C" void kernel_launch(void* const* d_in, const int* in_sizes, int n_in,
                              void* d_out, int out_size, void* d_ws, size_t ws_size,
                              hipStream_t stream) {
  const int* x = (const int*)d_in[0];
  const float* emb = (const float*)d_in[1];
  const float* pe = (const float*)d_in[2];
  const float* wq = (const float*)d_in[3];
  const float* wk = (const float*)d_in[4];
  const float* wv = (const float*)d_in[5];
  const float* g_h = (const float*)d_in[6];
  const float* b_h = (const float*)d_in[7];
  const float* wo = (const float*)d_in[8];
  const float* bo = (const float*)d_in[9];
  const float* g1 = (const float*)d_in[10];
  const float* bt1 = (const float*)d_in[11];
  const float* w1 = (const float*)d_in[12];
  const float* b1f = (const float*)d_in[13];
  const float* w2 = (const float*)d_in[14];
  const float* b2f = (const float*)d_in[15];
  const float* g2 = (const float*)d_in[16];
  const float* bt2 = (const float*)d_in[17];
  const float* gf = (const float*)d_in[18];
  const float* bff = (const float*)d_in[19];
  const float* wout = (const float*)d_in[20];
  const float* bout = (const float*)d_in[21];

  char* ws = (char*)d_ws;
  bf16_t* woutT = (bf16_t*)(ws + WOUTT_OFF);
  bf16_t* hbf = (bf16_t*)(ws + HBF_OFF);
  float* gsums = (float*)(ws + GSUM_OFF);
  unsigned long long* gmax = (unsigned long long*)(ws + GMAX_OFF);
  float* H = (float*)(ws + H_OFF);
  float* Q = (float*)(ws + Q_OFF);
  float* K = (float*)(ws + K_OFF);
  float* V = (float*)(ws + V_OFF);
  float* HO = (float*)(ws + HO_OFF);
  float* out = (float*)d_out;

  k_qkv<<<1588, 256, 0, stream>>>(x, emb, pe, wq, wk, wv, wout, woutT,
                                  H, Q, K, V, gsums, gmax, out);
  k_attn<<<dim3(64, 8), 256, 0, stream>>>(Q, K, V, HO);
  k_ffn<<<256, 256, 0, stream>>>(H, HO, g_h, b_h, wo, bo, g1, bt1, w1, b1f,
                                 w2, b2f, g2, bt2, gf, bff, hbf);
  dim3 grid(64, 8);
  k_sumexp<<<grid, 256, 0, stream>>>(hbf, woutT, bout, gsums, gmax);
  k_scatter<<<16, 256, 0, stream>>>(gsums, gmax, out);
}

// Round 7
// 756.876 us; speedup vs baseline: 1.2683x; 1.0006x over previous
//
#include <hip/hip_runtime.h>
#include <hip/hip_bf16.h>
#include <math.h>

#define EMB 64
#define SEQ 64
#define NH 8
#define DFF 256
#define VOC 32000
#define BATCH 64

using bf16_t = __hip_bfloat16;
typedef __bf16 bf16x8 __attribute__((ext_vector_type(8)));
typedef float f32x4 __attribute__((ext_vector_type(4)));

// ws layout (bytes)
#define WOUTT_OFF 0                     // bf16 [32000][64]  = 4,096,000 B
#define HBF_OFF   4194304               // bf16 [4096][64]   = 524,288 B
#define GSUM_OFF  (4194304 + 524288)    // f32  [4096]       = 16,384 B
#define GMAX_OFF  (GSUM_OFF + 16384)    // u64  [4096]       = 32,768 B
#define H_OFF     (GMAX_OFF + 32768)    // f32  [4096][64]   = 1 MB
#define Q_OFF     (H_OFF + 1048576)
#define K_OFF     (Q_OFF + 1048576)
#define V_OFF     (K_OFF + 1048576)
#define HO_OFF    (V_OFF + 1048576)     // ends at ~9.99 MB

// ---- out zero-fill partition (in f32x4 vectors; total 32,768,000) ----
// Spread across the 4 compute kernels so the mandatory 512 MB output fill
// overlaps compute instead of serializing at the head of the chain.
#define NV_TOTAL 32768000
#define F1_BLKS 360
#define F1_PER  32000                   // 360*32000 = 11,520,000
#define F2_BLKS 192                     // k_attn: 24 x-slots * 8 y
#define F2_PER  30000                   // 192*30000 =  5,760,000
#define F3_BLKS 360
#define F3_PER  32000                   // 360*32000 = 11,520,000
#define F4_BLKS 64                      // k_sumexp: 8 x-slots * 8 y
#define F4_PER  62000                   //  64*62000 =  3,968,000
#define F2_BASE 11520000
#define F3_BASE 17280000
#define F4_BASE 28800000

__device__ inline void fill_slice(float* __restrict__ outp, size_t vbase, int count, int t) {
  f32x4 z = {0.f, 0.f, 0.f, 0.f};
  f32x4* o4 = (f32x4*)outp + vbase;
  for (int i = t; i < count; i += 256) o4[i] = z;
}

// pack float (any sign) + index into an order-preserving u64 for atomicMax
__device__ inline unsigned long long packmax(float f, int i) {
  unsigned u = __float_as_uint(f);
  u = (u & 0x80000000u) ? ~u : (u | 0x80000000u);
  return ((unsigned long long)u << 32) | (unsigned)i;
}

__device__ inline float rsum16(float s) {
  s += __shfl_xor(s, 1, 16);
  s += __shfl_xor(s, 2, 16);
  s += __shfl_xor(s, 4, 16);
  s += __shfl_xor(s, 8, 16);
  return s;
}

// 64x64x64 GEMM from LDS (ld 65) to GLOBAL out (row stride 64), no bias
__device__ inline void gemm64g(const float* __restrict__ in, const float* __restrict__ W,
                               float* __restrict__ out, int t) {
  int i = t >> 2, j0 = (t & 3) * 16;
  float acc[16];
#pragma unroll
  for (int j = 0; j < 16; ++j) acc[j] = 0.f;
#pragma unroll 2
  for (int k = 0; k < 64; ++k) {
    float a = in[i * 65 + k];
    const float4* wr = (const float4*)(W + k * 64 + j0);
    float4 w0 = wr[0], w1v = wr[1], w2v = wr[2], w3v = wr[3];
    acc[0] += a * w0.x;   acc[1] += a * w0.y;   acc[2] += a * w0.z;   acc[3] += a * w0.w;
    acc[4] += a * w1v.x;  acc[5] += a * w1v.y;  acc[6] += a * w1v.z;  acc[7] += a * w1v.w;
    acc[8] += a * w2v.x;  acc[9] += a * w2v.y;  acc[10] += a * w2v.z; acc[11] += a * w2v.w;
    acc[12] += a * w3v.x; acc[13] += a * w3v.y; acc[14] += a * w3v.z; acc[15] += a * w3v.w;
  }
#pragma unroll
  for (int j = 0; j < 16; ++j) out[(size_t)i * 64 + j0 + j] = acc[j];
}

// ---------- K1: blocks 0..63 emb+pe -> H + QKV GEMMs; 64..563 wout transpose;
// 564..923 fill slice 1. ----------
__global__ __launch_bounds__(256) void k_qkv(
    const int* __restrict__ x, const float* __restrict__ emb, const float* __restrict__ pe,
    const float* __restrict__ wq, const float* __restrict__ wk, const float* __restrict__ wv,
    const float* __restrict__ wout, bf16_t* __restrict__ woutT,
    float* __restrict__ H, float* __restrict__ Q, float* __restrict__ K,
    float* __restrict__ V, float* __restrict__ gsums,
    unsigned long long* __restrict__ gmax, float* __restrict__ outp) {
  const int t = threadIdx.x;
  __shared__ float sm[64 * 65];

  if (blockIdx.x >= 564) {
    fill_slice(outp, (size_t)(blockIdx.x - 564) * F1_PER, F1_PER, t);
    return;
  }

  if (blockIdx.x >= 64) {
    // ---- transpose path: wout [64][32000] f32 -> woutT [32000][64] bf16 ----
    int v0 = (blockIdx.x - 64) * 64;
    for (int idx = t; idx < 4096; idx += 256) {
      int e = idx >> 6, c = idx & 63;
      sm[e * 65 + c] = wout[(size_t)e * VOC + v0 + c];
    }
    __syncthreads();
    for (int idx = t; idx < 4096; idx += 256) {
      int c = idx >> 6, e = idx & 63;
      woutT[(size_t)(v0 + c) * 64 + e] = __float2bfloat16(sm[e * 65 + c]);
    }
    return;
  }

  // ---- QKV path ----
  const int b = blockIdx.x;
  if (t < 64) {
    gsums[b * 64 + t] = 0.f;
    gmax[b * 64 + t] = 0ULL;
  }
  for (int idx = t; idx < 4096; idx += 256) {
    int i = idx >> 6, e = idx & 63;
    int tok = x[b * 64 + i];
    float v = emb[(size_t)tok * 64 + e] + pe[i * 64 + e];
    sm[i * 65 + e] = v;
    H[((size_t)b * 64 + i) * 64 + e] = v;
  }
  __syncthreads();
  gemm64g(sm, wq, Q + (size_t)b * 4096, t);
  gemm64g(sm, wk, K + (size_t)b * 4096, t);
  gemm64g(sm, wv, V + (size_t)b * 4096, t);
}

// ---------- K2: attention, one block per (b, head) for x<64; x>=64 fill slice 2. ----------
__global__ __launch_bounds__(256) void k_attn(const float* __restrict__ Q,
                                              const float* __restrict__ K,
                                              const float* __restrict__ V,
                                              float* __restrict__ HO,
                                              float* __restrict__ outp) {
  const int t = threadIdx.x;
  if (blockIdx.x >= 64) {
    int bid = (blockIdx.x - 64) * 8 + blockIdx.y;   // 0..191
    fill_slice(outp, (size_t)F2_BASE + (size_t)bid * F2_PER, F2_PER, t);
    return;
  }
  const int b = blockIdx.x, h = blockIdx.y;
  __shared__ float Qh[64 * 8], Kh[64 * 8], Vh[64 * 8];
  __shared__ float SC[64 * 65];
  const size_t base = (size_t)b * 4096 + h * 8;

  for (int idx = t; idx < 512; idx += 256) {
    int i = idx >> 3, d = idx & 7;
    Qh[i * 8 + d] = Q[base + (size_t)i * 64 + d];
    Kh[i * 8 + d] = K[base + (size_t)i * 64 + d];
    Vh[i * 8 + d] = V[base + (size_t)i * 64 + d];
  }
  __syncthreads();

  const float scale = 0.35355339059327373f;  // 1/sqrt(8)
  const int i = t >> 2, jb = t & 3;
  float qv[8];
#pragma unroll
  for (int d = 0; d < 8; ++d) qv[d] = Qh[i * 8 + d];

  float sv[16];
  float m = -INFINITY;
#pragma unroll
  for (int jj = 0; jj < 16; ++jj) {
    int j = jb * 16 + jj;
    float s;
    if (j <= i) {
      s = 0.f;
#pragma unroll
      for (int d = 0; d < 8; ++d) s += qv[d] * Kh[j * 8 + d];
      s *= scale;
    } else {
      s = -INFINITY;
    }
    sv[jj] = s;
    m = fmaxf(m, s);
  }
  m = fmaxf(m, __shfl_xor(m, 1, 4));
  m = fmaxf(m, __shfl_xor(m, 2, 4));
  float sum = 0.f;
#pragma unroll
  for (int jj = 0; jj < 16; ++jj) {
    float e2 = __expf(sv[jj] - m);
    sv[jj] = e2;
    sum += e2;
  }
  sum += __shfl_xor(sum, 1, 4);
  sum += __shfl_xor(sum, 2, 4);
  float inv = 1.f / sum;
#pragma unroll
  for (int jj = 0; jj < 16; ++jj) SC[i * 65 + jb * 16 + jj] = sv[jj] * inv;
  __syncthreads();

  for (int idx = t; idx < 512; idx += 256) {
    int ii = idx >> 3, d = idx & 7;
    float o = 0.f;
    for (int j = 0; j < 64; ++j) o += SC[ii * 65 + j] * Vh[j * 8 + d];
    HO[base + (size_t)ii * 64 + d] = rintf(o * 1e4f) / 1e4f;  // round4
  }
}

// ---------- K3: per-row LN/wo/residual/FFN/LN chain, 16 rows per block (x<256);
// x>=256 fill slice 3. ----------
__global__ __launch_bounds__(256) void k_ffn(
    const float* __restrict__ H, const float* __restrict__ HO,
    const float* __restrict__ g_h, const float* __restrict__ b_h,
    const float* __restrict__ wo, const float* __restrict__ bo,
    const float* __restrict__ g1, const float* __restrict__ bt1,
    const float* __restrict__ w1, const float* __restrict__ b1f,
    const float* __restrict__ w2, const float* __restrict__ b2f,
    const float* __restrict__ g2, const float* __restrict__ bt2,
    const float* __restrict__ gf, const float* __restrict__ bf_,
    bf16_t* __restrict__ hbf, float* __restrict__ outp) {
  const int t = threadIdx.x;
  if (blockIdx.x >= 256) {
    fill_slice(outp, (size_t)F3_BASE + (size_t)(blockIdx.x - 256) * F3_PER, F3_PER, t);
    return;
  }
  const int r0 = blockIdx.x * 16;
  const int i = t >> 4, l = t & 15;    // row-in-block, lane-in-row
  const int e0 = l * 4;
  const size_t row = (size_t)(r0 + i) * 64;
  __shared__ float T1[16 * 65];
  __shared__ float T2[16 * 65];
  __shared__ float H1[16 * 65];
  __shared__ float M[16 * 260];

  // A: ln_h = layernorm(HO; g_h, b_h) -> T1
  {
    float4 hv = *(const float4*)(HO + row + e0);
    float mu = rsum16(hv.x + hv.y + hv.z + hv.w) * (1.f / 64.f);
    float d0 = hv.x - mu, d1 = hv.y - mu, d2 = hv.z - mu, d3 = hv.w - mu;
    float var = rsum16(d0 * d0 + d1 * d1 + d2 * d2 + d3 * d3) * (1.f / 64.f);
    float rs = rsqrtf(var + 1e-5f);
    T1[i * 65 + e0 + 0] = d0 * rs * g_h[e0 + 0] + b_h[e0 + 0];
    T1[i * 65 + e0 + 1] = d1 * rs * g_h[e0 + 1] + b_h[e0 + 1];
    T1[i * 65 + e0 + 2] = d2 * rs * g_h[e0 + 2] + b_h[e0 + 2];
    T1[i * 65 + e0 + 3] = d3 * rs * g_h[e0 + 3] + b_h[e0 + 3];
  }
  __syncthreads();

  // B: attn_out = rint(T1 @ wo + bo) -> T2
  {
    float a0 = 0.f, a1 = 0.f, a2 = 0.f, a3 = 0.f;
#pragma unroll 4
    for (int k = 0; k < 64; ++k) {
      float a = T1[i * 65 + k];
      float4 w = *(const float4*)(wo + (size_t)k * 64 + e0);
      a0 += a * w.x; a1 += a * w.y; a2 += a * w.z; a3 += a * w.w;
    }
    T2[i * 65 + e0 + 0] = rintf(a0 + bo[e0 + 0]);
    T2[i * 65 + e0 + 1] = rintf(a1 + bo[e0 + 1]);
    T2[i * 65 + e0 + 2] = rintf(a2 + bo[e0 + 2]);
    T2[i * 65 + e0 + 3] = rintf(a3 + bo[e0 + 3]);
  }
  __syncthreads();

  // C: h1 = layernorm(H + attn_out; g1, bt1) -> H1
  {
    float4 hh = *(const float4*)(H + row + e0);
    float x0 = hh.x + T2[i * 65 + e0 + 0];
    float x1 = hh.y + T2[i * 65 + e0 + 1];
    float x2 = hh.z + T2[i * 65 + e0 + 2];
    float x3 = hh.w + T2[i * 65 + e0 + 3];
    float mu = rsum16(x0 + x1 + x2 + x3) * (1.f / 64.f);
    float d0 = x0 - mu, d1 = x1 - mu, d2 = x2 - mu, d3 = x3 - mu;
    float var = rsum16(d0 * d0 + d1 * d1 + d2 * d2 + d3 * d3) * (1.f / 64.f);
    float rs = rsqrtf(var + 1e-5f);
    H1[i * 65 + e0 + 0] = d0 * rs * g1[e0 + 0] + bt1[e0 + 0];
    H1[i * 65 + e0 + 1] = d1 * rs * g1[e0 + 1] + bt1[e0 + 1];
    H1[i * 65 + e0 + 2] = d2 * rs * g1[e0 + 2] + bt1[e0 + 2];
    H1[i * 65 + e0 + 3] = d3 * rs * g1[e0 + 3] + bt1[e0 + 3];
  }
  __syncthreads();

  // D: M = relu(H1 @ w1 + b1f), 16 outputs per thread (j0 = l*16)
  {
    const int j0 = l * 16;
    float acc[16];
#pragma unroll
    for (int j = 0; j < 16; ++j) acc[j] = 0.f;
#pragma unroll 2
    for (int k = 0; k < 64; ++k) {
      float a = H1[i * 65 + k];
      const float4* wr = (const float4*)(w1 + (size_t)k * 256 + j0);
      float4 w0 = wr[0], w1v = wr[1], w2v = wr[2], w3v = wr[3];
      acc[0] += a * w0.x;   acc[1] += a * w0.y;   acc[2] += a * w0.z;   acc[3] += a * w0.w;
      acc[4] += a * w1v.x;  acc[5] += a * w1v.y;  acc[6] += a * w1v.z;  acc[7] += a * w1v.w;
      acc[8] += a * w2v.x;  acc[9] += a * w2v.y;  acc[10] += a * w2v.z; acc[11] += a * w2v.w;
      acc[12] += a * w3v.x; acc[13] += a * w3v.y; acc[14] += a * w3v.z; acc[15] += a * w3v.w;
    }
#pragma unroll
    for (int j = 0; j < 16; ++j)
      M[i * 260 + j0 + j] = fmaxf(acc[j] + b1f[j0 + j], 0.f);
  }
  __syncthreads();

  // E: ffn = M @ w2 + b2f (kept in regs)
  float f0 = 0.f, f1 = 0.f, f2 = 0.f, f3 = 0.f;
  {
#pragma unroll 4
    for (int k = 0; k < 256; ++k) {
      float a = M[i * 260 + k];
      float4 w = *(const float4*)(w2 + (size_t)k * 64 + e0);
      f0 += a * w.x; f1 += a * w.y; f2 += a * w.z; f3 += a * w.w;
    }
    f0 += b2f[e0 + 0]; f1 += b2f[e0 + 1]; f2 += b2f[e0 + 2]; f3 += b2f[e0 + 3];
  }

  // F: h2 = round4(layernorm(H1 + ffn; g2, bt2)); hf = layernorm(h2; gf, bf) -> hbf
  {
    float y0 = H1[i * 65 + e0 + 0] + f0;
    float y1 = H1[i * 65 + e0 + 1] + f1;
    float y2 = H1[i * 65 + e0 + 2] + f2;
    float y3 = H1[i * 65 + e0 + 3] + f3;
    float mu = rsum16(y0 + y1 + y2 + y3) * (1.f / 64.f);
    float d0 = y0 - mu, d1 = y1 - mu, d2 = y2 - mu, d3 = y3 - mu;
    float var = rsum16(d0 * d0 + d1 * d1 + d2 * d2 + d3 * d3) * (1.f / 64.f);
    float rs = rsqrtf(var + 1e-5f);
    float h20 = rintf((d0 * rs * g2[e0 + 0] + bt2[e0 + 0]) * 1e4f) / 1e4f;
    float h21 = rintf((d1 * rs * g2[e0 + 1] + bt2[e0 + 1]) * 1e4f) / 1e4f;
    float h22 = rintf((d2 * rs * g2[e0 + 2] + bt2[e0 + 2]) * 1e4f) / 1e4f;
    float h23 = rintf((d3 * rs * g2[e0 + 3] + bt2[e0 + 3]) * 1e4f) / 1e4f;
    float mu2 = rsum16(h20 + h21 + h22 + h23) * (1.f / 64.f);
    float e0d = h20 - mu2, e1d = h21 - mu2, e2d = h22 - mu2, e3d = h23 - mu2;
    float var2 = rsum16(e0d * e0d + e1d * e1d + e2d * e2d + e3d * e3d) * (1.f / 64.f);
    float rs2 = rsqrtf(var2 + 1e-5f);
    hbf[row + e0 + 0] = __float2bfloat16(e0d * rs2 * gf[e0 + 0] + bf_[e0 + 0]);
    hbf[row + e0 + 1] = __float2bfloat16(e1d * rs2 * gf[e0 + 1] + bf_[e0 + 1]);
    hbf[row + e0 + 2] = __float2bfloat16(e2d * rs2 * gf[e0 + 2] + bf_[e0 + 2]);
    hbf[row + e0 + 3] = __float2bfloat16(e3d * rs2 * gf[e0 + 3] + bf_[e0 + 3]);
  }
}

// ---------- kernel A: per-row sum of exp(logit) over V + running argmax, MFMA.
// x<64: compute (64 rows per block, 8 vocab slices in y); x>=64: fill slice 4. ----------
__global__ __launch_bounds__(256) void k_sumexp(const bf16_t* __restrict__ hbf,
                                                const bf16_t* __restrict__ woutT,
                                                const float* __restrict__ bout,
                                                float* __restrict__ gsums,
                                                unsigned long long* __restrict__ gmax,
                                                float* __restrict__ outp) {
  const int t = threadIdx.x;
  if (blockIdx.x >= 64) {
    int bid = (blockIdx.x - 64) * 8 + blockIdx.y;   // 0..63
    fill_slice(outp, (size_t)F4_BASE + (size_t)bid * F4_PER, F4_PER, t);
    return;
  }
  const int lane = t & 63, wave = t >> 6;
  const int row0 = blockIdx.x * 64;
  const int nbase = blockIdx.y * 4000;
  const int mrow = lane & 15, quad = lane >> 4;
  __shared__ float lsum[64];
  if (t < 64) lsum[t] = 0.f;
  __syncthreads();

  bf16x8 a0[4], a1[4];
#pragma unroll
  for (int at = 0; at < 4; ++at) {
    const bf16_t* arow = hbf + (size_t)(row0 + at * 16 + mrow) * 64 + quad * 8;
    a0[at] = *(const bf16x8*)(arow);
    a1[at] = *(const bf16x8*)(arow + 32);
  }

  float s[4][4];
  float mxv[4][4];
  int mxi[4][4];
#pragma unroll
  for (int at = 0; at < 4; ++at)
#pragma unroll
    for (int r = 0; r < 4; ++r) { s[at][r] = 0.f; mxv[at][r] = -INFINITY; mxi[at][r] = 0; }

  for (int tt = wave; tt < 250; tt += 4) {
    int col = nbase + tt * 16 + mrow;
    const bf16_t* brow = woutT + (size_t)col * 64 + quad * 8;
    bf16x8 b0 = *(const bf16x8*)(brow);
    bf16x8 b1 = *(const bf16x8*)(brow + 32);
    float bv = bout[col];
#pragma unroll
    for (int at = 0; at < 4; ++at) {
      f32x4 c = {0.f, 0.f, 0.f, 0.f};
      c = __builtin_amdgcn_mfma_f32_16x16x32_bf16(a0[at], b0, c, 0, 0, 0);
      c = __builtin_amdgcn_mfma_f32_16x16x32_bf16(a1[at], b1, c, 0, 0, 0);
#pragma unroll
      for (int r = 0; r < 4; ++r) {
        float v = c[r] + bv;
        s[at][r] += __expf(v);
        mxi[at][r] = (v > mxv[at][r]) ? col : mxi[at][r];
        mxv[at][r] = fmaxf(mxv[at][r], v);
      }
    }
  }
#pragma unroll
  for (int off = 1; off < 16; off <<= 1) {
#pragma unroll
    for (int at = 0; at < 4; ++at)
#pragma unroll
      for (int r = 0; r < 4; ++r) {
        s[at][r] += __shfl_xor(s[at][r], off, 64);
        float ov = __shfl_xor(mxv[at][r], off, 64);
        int oi = __shfl_xor(mxi[at][r], off, 64);
        if (ov > mxv[at][r] || (ov == mxv[at][r] && oi > mxi[at][r])) {
          mxv[at][r] = ov; mxi[at][r] = oi;
        }
      }
  }
  if (mrow == 0) {
#pragma unroll
    for (int at = 0; at < 4; ++at)
#pragma unroll
      for (int r = 0; r < 4; ++r) {
        atomicAdd(&lsum[at * 16 + quad * 4 + r], s[at][r]);
        atomicMax(&gmax[row0 + at * 16 + quad * 4 + r], packmax(mxv[at][r], mxi[at][r]));
      }
  }
  __syncthreads();
  if (t < 64) atomicAdd(&gsums[row0 + t], lsum[t]);
}

// ---------- kernel B: scatter the (at most one) nonzero per row ----------
__global__ __launch_bounds__(256) void k_scatter(const float* __restrict__ gsums,
                                                 const unsigned long long* __restrict__ gmax,
                                                 float* __restrict__ out) {
  int row = blockIdx.x * 256 + threadIdx.x;
  if (row >= BATCH * SEQ) return;
  unsigned long long p = gmax[row];
  unsigned key = (unsigned)(p >> 32);
  int idx = (int)(p & 0xffffffffu);
  unsigned ub = (key & 0x80000000u) ? (key & 0x7fffffffu) : ~key;
  float lmax = __uint_as_float(ub);
  float iv = 1.0f / gsums[row];
  float v = rintf(__expf(lmax) * iv);
  if (v != 0.0f) out[(size_t)row * VOC + idx] = v;
}

extern "C" void kernel_launch(void* const* d_in, const int* in_sizes, int n_in,
                              void* d_out, int out_size, void* d_ws, size_t ws_size,
                              hipStream_t stream) {
  const int* x = (const int*)d_in[0];
  const float* emb = (const float*)d_in[1];
  const float* pe = (const float*)d_in[2];
  const float* wq = (const float*)d_in[3];
  const float* wk = (const float*)d_in[4];
  const float* wv = (const float*)d_in[5];
  const float* g_h = (const float*)d_in[6];
  const float* b_h = (const float*)d_in[7];
  const float* wo = (const float*)d_in[8];
  const float* bo = (const float*)d_in[9];
  const float* g1 = (const float*)d_in[10];
  const float* bt1 = (const float*)d_in[11];
  const float* w1 = (const float*)d_in[12];
  const float* b1f = (const float*)d_in[13];
  const float* w2 = (const float*)d_in[14];
  const float* b2f = (const float*)d_in[15];
  const float* g2 = (const float*)d_in[16];
  const float* bt2 = (const float*)d_in[17];
  const float* gf = (const float*)d_in[18];
  const float* bff = (const float*)d_in[19];
  const float* wout = (const float*)d_in[20];
  const float* bout = (const float*)d_in[21];

  char* ws = (char*)d_ws;
  bf16_t* woutT = (bf16_t*)(ws + WOUTT_OFF);
  bf16_t* hbf = (bf16_t*)(ws + HBF_OFF);
  float* gsums = (float*)(ws + GSUM_OFF);
  unsigned long long* gmax = (unsigned long long*)(ws + GMAX_OFF);
  float* H = (float*)(ws + H_OFF);
  float* Q = (float*)(ws + Q_OFF);
  float* K = (float*)(ws + K_OFF);
  float* V = (float*)(ws + V_OFF);
  float* HO = (float*)(ws + HO_OFF);
  float* out = (float*)d_out;

  k_qkv<<<564 + F1_BLKS, 256, 0, stream>>>(x, emb, pe, wq, wk, wv, wout, woutT,
                                           H, Q, K, V, gsums, gmax, out);
  k_attn<<<dim3(64 + F2_BLKS / 8, 8), 256, 0, stream>>>(Q, K, V, HO, out);
  k_ffn<<<256 + F3_BLKS, 256, 0, stream>>>(H, HO, g_h, b_h, wo, bo, g1, bt1, w1, b1f,
                                           w2, b2f, g2, bt2, gf, bff, hbf, out);
  dim3 grid(64 + F4_BLKS / 8, 8);
  k_sumexp<<<grid, 256, 0, stream>>>(hbf, woutT, bout, gsums, gmax, out);
  k_scatter<<<16, 256, 0, stream>>>(gsums, gmax, out);
}